// Round 1
// baseline (901.027 us; speedup 1.0000x reference)
//
#include <hip/hip_runtime.h>

typedef unsigned short u16;
typedef unsigned int   u32;
typedef __attribute__((ext_vector_type(8))) __bf16 bf16x8;
typedef __attribute__((ext_vector_type(4))) float  f32x4;

#define BQ   8
#define SQ   4096
#define NHQ  16
#define HIDD 1024
#define TOKN 32768

__device__ __forceinline__ u16 f2bf(float f){
  u32 u = __builtin_bit_cast(u32, f);
  u += 0x7fffu + ((u >> 16) & 1u);
  return (u16)(u >> 16);
}
__device__ __forceinline__ float bf2f(u16 h){
  return __builtin_bit_cast(float, (u32)h << 16);
}
__device__ __forceinline__ void gl16(const void* g, void* l){
  __builtin_amdgcn_global_load_lds((const __attribute__((address_space(1))) void*)g,
                                   (__attribute__((address_space(3))) void*)l, 16, 0, 0);
}

// ---------------- fp32 -> bf16 cast (weights) ----------------
__global__ __launch_bounds__(256) void k_cast(const float* __restrict__ in, u16* __restrict__ o){
  int i = blockIdx.x * 256 + threadIdx.x;
  float4 v = ((const float4*)in)[i];
  ushort4 r;
  r.x = f2bf(v.x); r.y = f2bf(v.y); r.z = f2bf(v.z); r.w = f2bf(v.w);
  ((ushort4*)o)[i] = r;
}

// ---------------- LayerNorm + cast x / x_norm ----------------
__global__ __launch_bounds__(256) void k_ln(const float* __restrict__ x, const float* __restrict__ g,
    const float* __restrict__ be, u16* __restrict__ xbf, u16* __restrict__ xnbf){
  const int row = blockIdx.x, t = threadIdx.x;
  const float4 v = ((const float4*)(x + (size_t)row * HIDD))[t];
  float s  = v.x + v.y + v.z + v.w;
  float ss = v.x*v.x + v.y*v.y + v.z*v.z + v.w*v.w;
  #pragma unroll
  for (int o = 1; o < 64; o <<= 1){ s += __shfl_xor(s, o); ss += __shfl_xor(ss, o); }
  __shared__ float sm[8];
  const int lane = t & 63, wid = t >> 6;
  if (lane == 0){ sm[wid] = s; sm[wid + 4] = ss; }
  __syncthreads();
  s  = sm[0] + sm[1] + sm[2] + sm[3];
  ss = sm[4] + sm[5] + sm[6] + sm[7];
  const float mu   = s * (1.f / 1024.f);
  const float var  = ss * (1.f / 1024.f) - mu * mu;
  const float rstd = rsqrtf(var + 1e-12f);
  const float4 gg = ((const float4*)g)[t];
  const float4 bb = ((const float4*)be)[t];
  ushort4 xo, no;
  xo.x = f2bf(v.x); no.x = f2bf((v.x - mu) * rstd * gg.x + bb.x);
  xo.y = f2bf(v.y); no.y = f2bf((v.y - mu) * rstd * gg.y + bb.y);
  xo.z = f2bf(v.z); no.z = f2bf((v.z - mu) * rstd * gg.z + bb.z);
  xo.w = f2bf(v.w); no.w = f2bf((v.w - mu) * rstd * gg.w + bb.w);
  ((ushort4*)(xbf  + (size_t)row * HIDD))[t] = xo;
  ((ushort4*)(xnbf + (size_t)row * HIDD))[t] = no;
}

// ---------------- big NT GEMM: C[M,N] = A[M,K] * W[N,K]^T + bias (+resid) ----------------
// 128x128 tile, BK=32, 4 waves (2x2), m97-style global_load_lds staging, double-buffered.
// LDS chunk layout: chunk c (16B = 8 bf16) = (g = c>>7, row = c&127): A[row][k0+g*8 .. +8]
template<int RES>
__global__ __launch_bounds__(256) void k_gemm_bt(const u16* __restrict__ A,
    const u16* __restrict__ W, const float* __restrict__ bias,
    const float* __restrict__ resid, u16* __restrict__ outb, float* __restrict__ outf){
  __shared__ u16 lds[2][2][4096];   // [buf][A/B][512 chunks * 8] = 32 KiB
  const int m0 = blockIdx.x << 7, n0 = blockIdx.y << 7;
  const int t = threadIdx.x, lane = t & 63, wid = t >> 6;
  const int ln15 = lane & 15, hi = lane >> 4;
  const int wr = wid >> 1, wc = wid & 1;

  auto stage = [&](int buf, int kt){
    const int k0 = kt << 5;
    #pragma unroll
    for (int i = 0; i < 2; i++){
      int c = (wid << 6) + (i << 8) + lane;
      int g = c >> 7, row = c & 127;
      gl16(A + (size_t)(m0 + row) * HIDD + k0 + g * 8, &lds[buf][0][((wid << 6) + (i << 8)) * 8]);
    }
    #pragma unroll
    for (int i = 0; i < 2; i++){
      int c = (wid << 6) + (i << 8) + lane;
      int g = c >> 7, row = c & 127;
      gl16(W + (size_t)(n0 + row) * HIDD + k0 + g * 8, &lds[buf][1][((wid << 6) + (i << 8)) * 8]);
    }
  };

  f32x4 acc[4][4] = {};
  stage(0, 0);
  asm volatile("s_waitcnt vmcnt(0)" ::: "memory");
  __syncthreads();
  int cur = 0;
  const int NT = HIDD / 32;
  for (int kt = 0; kt < NT; ++kt){
    if (kt + 1 < NT) stage(cur ^ 1, kt + 1);
    const bf16x8* Ab = (const bf16x8*)lds[cur][0];
    const bf16x8* Bb = (const bf16x8*)lds[cur][1];
    bf16x8 af[4], bfr[4];
    const int ci = (hi << 7) + ln15;
    #pragma unroll
    for (int m = 0; m < 4; m++) af[m]  = Ab[ci + (wr << 6) + (m << 4)];
    #pragma unroll
    for (int n = 0; n < 4; n++) bfr[n] = Bb[ci + (wc << 6) + (n << 4)];
    #pragma unroll
    for (int m = 0; m < 4; m++)
      #pragma unroll
      for (int n = 0; n < 4; n++)
        acc[m][n] = __builtin_amdgcn_mfma_f32_16x16x32_bf16(af[m], bfr[n], acc[m][n], 0, 0, 0);
    __syncthreads();   // drains vmcnt (staged tile ready) + protects LDS reuse
    cur ^= 1;
  }
  // C/D layout: col = lane&15, row = 4*(lane>>4)+r
  const int rbase = m0 + (wr << 6) + (hi << 2);
  const int cbase = n0 + (wc << 6) + ln15;
  #pragma unroll
  for (int n = 0; n < 4; n++){
    int col = cbase + (n << 4);
    float bc = bias[col];
    #pragma unroll
    for (int m = 0; m < 4; m++){
      #pragma unroll
      for (int r = 0; r < 4; r++){
        int row = rbase + (m << 4) + r;
        float v = acc[m][n][r] + bc;
        if constexpr (RES)
          outf[(size_t)row * HIDD + col] = v + resid[(size_t)row * HIDD + col];
        else
          outb[(size_t)row * HIDD + col] = f2bf(v);
      }
    }
  }
}

// ---------------- elu + L2 norm over head_dim (in-place, q) ----------------
__global__ __launch_bounds__(256) void k_elunorm(u16* __restrict__ q){
  size_t idx = (size_t)blockIdx.x * 256 + threadIdx.x;  // one 8-elem chunk; 8 lanes = 1 token-head
  uint4 u = ((const uint4*)q)[idx];
  u32 uu[4] = {u.x, u.y, u.z, u.w};
  float e[8]; float ss = 0.f;
  #pragma unroll
  for (int i = 0; i < 4; i++){
    float f0 = bf2f((u16)(uu[i] & 0xffff));
    float f1 = bf2f((u16)(uu[i] >> 16));
    f0 = f0 > 0.f ? f0 : expm1f(f0);
    f1 = f1 > 0.f ? f1 : expm1f(f1);
    e[2*i] = f0; e[2*i+1] = f1;
    ss += f0 * f0 + f1 * f1;
  }
  ss += __shfl_xor(ss, 1); ss += __shfl_xor(ss, 2); ss += __shfl_xor(ss, 4);
  float rn = rsqrtf(ss);
  u32 ro[4];
  #pragma unroll
  for (int i = 0; i < 4; i++)
    ro[i] = (u32)f2bf(e[2*i] * rn) | ((u32)f2bf(e[2*i+1] * rn) << 16);
  uint4 o; o.x = ro[0]; o.y = ro[1]; o.z = ro[2]; o.w = ro[3];
  ((uint4*)q)[idx] = o;
}

// ---------------- transpose [B,S,H,64] -> [B,H,64,S], optional elu+L2norm ----------------
template<int ELU>
__global__ __launch_bounds__(256) void k_transpose(const u16* __restrict__ in, u16* __restrict__ outp){
  __shared__ float tile[64][65];
  __shared__ float pr[64][4];
  __shared__ float rn[64];
  const int sb = blockIdx.x << 6, h = blockIdx.y, b = blockIdx.z;
  const int t = threadIdx.x;
  {
    const int tok = t >> 2, q = t & 3;
    const u16* src = in + (size_t)(b * SQ + sb + tok) * HIDD + (h << 6) + (q << 4);
    uint4 u0 = *(const uint4*)src;
    uint4 u1 = *(const uint4*)(src + 8);
    u32 uu[8] = {u0.x, u0.y, u0.z, u0.w, u1.x, u1.y, u1.z, u1.w};
    float ss = 0.f;
    #pragma unroll
    for (int i = 0; i < 8; i++){
      float f0 = bf2f((u16)(uu[i] & 0xffff));
      float f1 = bf2f((u16)(uu[i] >> 16));
      if (ELU){
        f0 = f0 > 0.f ? f0 : expm1f(f0);
        f1 = f1 > 0.f ? f1 : expm1f(f1);
        ss += f0 * f0 + f1 * f1;
      }
      tile[tok][(q << 4) + 2*i]     = f0;
      tile[tok][(q << 4) + 2*i + 1] = f1;
    }
    if (ELU) pr[tok][q] = ss;
  }
  __syncthreads();
  if (ELU){
    if (t < 64) rn[t] = rsqrtf(pr[t][0] + pr[t][1] + pr[t][2] + pr[t][3]);
    __syncthreads();
  }
  const int d = t >> 2, sq2 = (t & 3) << 4;
  u16* dst = outp + ((size_t)(b * NHQ + h) * 64 + d) * SQ + sb + sq2;
  u32 ro[8];
  #pragma unroll
  for (int i = 0; i < 8; i++){
    float v0 = tile[sq2 + 2*i][d];
    float v1 = tile[sq2 + 2*i + 1][d];
    if (ELU){ v0 *= rn[sq2 + 2*i]; v1 *= rn[sq2 + 2*i + 1]; }
    ro[i] = (u32)f2bf(v0) | ((u32)f2bf(v1) << 16);
  }
  uint4 o0; o0.x = ro[0]; o0.y = ro[1]; o0.z = ro[2]; o0.w = ro[3];
  uint4 o1; o1.x = ro[4]; o1.y = ro[5]; o1.z = ro[6]; o1.w = ro[7];
  *(uint4*)dst = o0;
  *(uint4*)(dst + 8) = o1;
}

// ---------------- kv: per (b,h)  kvT[e][d] = (1/8) * sum_s v[s][e] ek[s][d] ----------------
// A = vT rows (e), B = ekT rows (d); 4 waves split K=4096; LDS cross-wave reduce.
__global__ __launch_bounds__(256) void k_kv(const u16* __restrict__ vT, const u16* __restrict__ ekT,
                                            u16* __restrict__ kvT){
  const int bh = blockIdx.x;
  const u16* Av = vT  + (size_t)bh * 64 * SQ;
  const u16* Bk = ekT + (size_t)bh * 64 * SQ;
  const int lane = threadIdx.x & 63, wid = threadIdx.x >> 6;
  const int ln15 = lane & 15, hi = lane >> 4;
  f32x4 acc[4][4] = {};
  const int kb = wid << 10;
  for (int ks = 0; ks < 32; ++ks){
    const int k0 = kb + (ks << 5) + (hi << 3);
    bf16x8 af[4], bfr[4];
    #pragma unroll
    for (int m = 0; m < 4; m++) af[m]  = *(const bf16x8*)(Av + (size_t)((m << 4) + ln15) * SQ + k0);
    #pragma unroll
    for (int n = 0; n < 4; n++) bfr[n] = *(const bf16x8*)(Bk + (size_t)((n << 4) + ln15) * SQ + k0);
    #pragma unroll
    for (int m = 0; m < 4; m++)
      #pragma unroll
      for (int n = 0; n < 4; n++)
        acc[m][n] = __builtin_amdgcn_mfma_f32_16x16x32_bf16(af[m], bfr[n], acc[m][n], 0, 0, 0);
  }
  __shared__ float red[64][64];
  for (int w = 0; w < 4; ++w){
    if (wid == w){
      #pragma unroll
      for (int m = 0; m < 4; m++)
        #pragma unroll
        for (int n = 0; n < 4; n++)
          #pragma unroll
          for (int r = 0; r < 4; r++){
            int row = (m << 4) + (hi << 2) + r;   // e
            int col = (n << 4) + ln15;            // d
            if (w == 0) red[row][col] = acc[m][n][r];
            else        red[row][col] += acc[m][n][r];
          }
    }
    __syncthreads();
  }
  u16* dst = kvT + (size_t)bh * 4096;
  const int tt = threadIdx.x;
  #pragma unroll
  for (int i = 0; i < 16; i++){
    int idx = tt * 16 + i;
    dst[idx] = f2bf(red[idx >> 6][idx & 63] * 0.125f);
  }
}

// ---------------- ctx: per (b,h,sblock) ctx[s][e] = sum_d eq[s][d] * kv[d][e] ----------------
__global__ __launch_bounds__(256) void k_ctx(const u16* __restrict__ eq, const u16* __restrict__ kvT,
                                             u16* __restrict__ ctx){
  __shared__ u16 Alds[1024 * 8];  // 16 KiB: chunk (g = c>>7, row = c&127)
  __shared__ u16 Blds[512 * 8];   //  8 KiB: chunk (g = c>>6, row = c&63)
  const int sb = blockIdx.x << 7;
  const int h = blockIdx.y, b = blockIdx.z;
  const int bh = (b << 4) + h;
  const int t = threadIdx.x, lane = t & 63, wid = t >> 6;
  const int ln15 = lane & 15, hi = lane >> 4;
  #pragma unroll
  for (int i = 0; i < 4; i++){
    int c = (wid << 6) + (i << 8) + lane;
    int g = c >> 7, row = c & 127;
    gl16(eq + (size_t)(b * SQ + sb + row) * HIDD + (h << 6) + g * 8,
         &Alds[((wid << 6) + (i << 8)) * 8]);
  }
  #pragma unroll
  for (int i = 0; i < 2; i++){
    int c = (wid << 6) + (i << 8) + lane;
    int g = c >> 6, row = c & 63;
    gl16(kvT + (size_t)bh * 4096 + (row << 6) + g * 8,
         &Blds[((wid << 6) + (i << 8)) * 8]);
  }
  asm volatile("s_waitcnt vmcnt(0)" ::: "memory");
  __syncthreads();
  f32x4 acc[2][4] = {};
  #pragma unroll
  for (int k2 = 0; k2 < 2; k2++){
    const int g = (k2 << 2) + hi;
    bf16x8 af[2], bfr[4];
    #pragma unroll
    for (int m = 0; m < 2; m++) af[m]  = *(const bf16x8*)&Alds[((g << 7) + (wid << 5) + (m << 4) + ln15) * 8];
    #pragma unroll
    for (int n = 0; n < 4; n++) bfr[n] = *(const bf16x8*)&Blds[((g << 6) + (n << 4) + ln15) * 8];
    #pragma unroll
    for (int m = 0; m < 2; m++)
      #pragma unroll
      for (int n = 0; n < 4; n++)
        acc[m][n] = __builtin_amdgcn_mfma_f32_16x16x32_bf16(af[m], bfr[n], acc[m][n], 0, 0, 0);
  }
  #pragma unroll
  for (int m = 0; m < 2; m++)
    #pragma unroll
    for (int n = 0; n < 4; n++)
      #pragma unroll
      for (int r = 0; r < 4; r++){
        int srow = sb + (wid << 5) + (m << 4) + (hi << 2) + r;
        int col  = (n << 4) + ln15;
        ctx[(size_t)(b * SQ + srow) * HIDD + (h << 6) + col] = f2bf(acc[m][n][r]);
      }
}

extern "C" void kernel_launch(void* const* d_in, const int* in_sizes, int n_in,
                              void* d_out, int out_size, void* d_ws, size_t ws_size,
                              hipStream_t stream){
  const float* x   = (const float*)d_in[0];
  // d_in[1] attention_mask: unused (matches reference)
  const float* lng = (const float*)d_in[2];
  const float* lnb = (const float*)d_in[3];
  const float* Wq  = (const float*)d_in[4];
  const float* bq  = (const float*)d_in[5];
  const float* Wk  = (const float*)d_in[6];
  const float* bk  = (const float*)d_in[7];
  const float* Wv  = (const float*)d_in[8];
  const float* bv  = (const float*)d_in[9];
  const float* Wo  = (const float*)d_in[10];
  const float* bo  = (const float*)d_in[11];
  float* out = (float*)d_out;

  char* w = (char*)d_ws;
  const size_t MB = 1ull << 20;
  u16* wqb  = (u16*)(w + 0   * MB);   // 2 MiB each
  u16* wkb  = (u16*)(w + 2   * MB);
  u16* wvb  = (u16*)(w + 4   * MB);
  u16* wob  = (u16*)(w + 6   * MB);
  u16* xbf  = (u16*)(w + 8   * MB);   // 64 MiB each token buffer
  u16* xnbf = (u16*)(w + 72  * MB);
  u16* qb   = (u16*)(w + 136 * MB);
  u16* kb   = (u16*)(w + 200 * MB);
  u16* vb   = (u16*)(w + 264 * MB);
  u16* kvT  = (u16*)(w + 328 * MB);   // 1 MiB
  // aliases (stream-ordered lifetimes)
  u16* ekT = xnbf;  // xnbf dead after Q GEMM
  u16* vT  = xbf;   // xbf dead after K/V GEMMs
  u16* ctx = kb;    // k_bf dead after transpose<1>

  k_cast<<<1024, 256, 0, stream>>>(Wq, wqb);
  k_cast<<<1024, 256, 0, stream>>>(Wk, wkb);
  k_cast<<<1024, 256, 0, stream>>>(Wv, wvb);
  k_cast<<<1024, 256, 0, stream>>>(Wo, wob);
  k_ln<<<TOKN, 256, 0, stream>>>(x, lng, lnb, xbf, xnbf);
  dim3 gg(256, 8);
  k_gemm_bt<0><<<gg, 256, 0, stream>>>(xnbf, wqb, bq, nullptr, qb, nullptr);
  k_gemm_bt<0><<<gg, 256, 0, stream>>>(xbf,  wkb, bk, nullptr, kb, nullptr);
  k_gemm_bt<0><<<gg, 256, 0, stream>>>(xbf,  wvb, bv, nullptr, vb, nullptr);
  k_elunorm<<<16384, 256, 0, stream>>>(qb);
  k_transpose<1><<<dim3(64, 16, 8), 256, 0, stream>>>(kb, ekT);
  k_transpose<0><<<dim3(64, 16, 8), 256, 0, stream>>>(vb, vT);
  k_kv<<<128, 256, 0, stream>>>(vT, ekT, kvT);
  k_ctx<<<dim3(32, 16, 8), 256, 0, stream>>>(qb, kvT, ctx);
  k_gemm_bt<1><<<gg, 256, 0, stream>>>(ctx, wob, bo, x, nullptr, out);

  (void)in_sizes; (void)n_in; (void)out_size; (void)ws_size;
}

// Round 2
// 754.080 us; speedup vs baseline: 1.1949x; 1.1949x over previous
//
#include <hip/hip_runtime.h>

typedef unsigned short u16;
typedef unsigned int   u32;
typedef __attribute__((ext_vector_type(8))) __bf16 bf16x8;
typedef __attribute__((ext_vector_type(4))) float  f32x4;

#define BQ   8
#define SQ   4096
#define NHQ  16
#define HIDD 1024
#define TOKN 32768

__device__ __forceinline__ u16 f2bf(float f){
  u32 u = __builtin_bit_cast(u32, f);
  u += 0x7fffu + ((u >> 16) & 1u);
  return (u16)(u >> 16);
}
__device__ __forceinline__ float bf2f(u16 h){
  return __builtin_bit_cast(float, (u32)h << 16);
}
__device__ __forceinline__ void gl16(const void* g, void* l){
  __builtin_amdgcn_global_load_lds((const __attribute__((address_space(1))) void*)g,
                                   (__attribute__((address_space(3))) void*)l, 16, 0, 0);
}
#define MFMA(a,b,c) __builtin_amdgcn_mfma_f32_16x16x32_bf16((a),(b),(c),0,0,0)

// ---------------- fp32 -> bf16 cast (weights) ----------------
__global__ __launch_bounds__(256) void k_cast(const float* __restrict__ in, u16* __restrict__ o){
  int i = blockIdx.x * 256 + threadIdx.x;
  float4 v = ((const float4*)in)[i];
  ushort4 r;
  r.x = f2bf(v.x); r.y = f2bf(v.y); r.z = f2bf(v.z); r.w = f2bf(v.w);
  ((ushort4*)o)[i] = r;
}

// ---------------- LayerNorm + cast x / x_norm ----------------
__global__ __launch_bounds__(256) void k_ln(const float* __restrict__ x, const float* __restrict__ g,
    const float* __restrict__ be, u16* __restrict__ xbf, u16* __restrict__ xnbf){
  const int row = blockIdx.x, t = threadIdx.x;
  const float4 v = ((const float4*)(x + (size_t)row * HIDD))[t];
  float s  = v.x + v.y + v.z + v.w;
  float ss = v.x*v.x + v.y*v.y + v.z*v.z + v.w*v.w;
  #pragma unroll
  for (int o = 1; o < 64; o <<= 1){ s += __shfl_xor(s, o); ss += __shfl_xor(ss, o); }
  __shared__ float sm[8];
  const int lane = t & 63, wid = t >> 6;
  if (lane == 0){ sm[wid] = s; sm[wid + 4] = ss; }
  __syncthreads();
  s  = sm[0] + sm[1] + sm[2] + sm[3];
  ss = sm[4] + sm[5] + sm[6] + sm[7];
  const float mu   = s * (1.f / 1024.f);
  const float var  = ss * (1.f / 1024.f) - mu * mu;
  const float rstd = rsqrtf(var + 1e-12f);
  const float4 gg = ((const float4*)g)[t];
  const float4 bb = ((const float4*)be)[t];
  ushort4 xo, no;
  xo.x = f2bf(v.x); no.x = f2bf((v.x - mu) * rstd * gg.x + bb.x);
  xo.y = f2bf(v.y); no.y = f2bf((v.y - mu) * rstd * gg.y + bb.y);
  xo.z = f2bf(v.z); no.z = f2bf((v.z - mu) * rstd * gg.z + bb.z);
  xo.w = f2bf(v.w); no.w = f2bf((v.w - mu) * rstd * gg.w + bb.w);
  ((ushort4*)(xbf  + (size_t)row * HIDD))[t] = xo;
  ((ushort4*)(xnbf + (size_t)row * HIDD))[t] = no;
}

// ---------------- big NT GEMM: C[M,N] = A[M,K] * W[N,K]^T + bias (+resid) ----------------
// 256x256 tile, BK=64, 8 waves (2Mx4N), 512 thr. 2 phases/K-tile, counted vmcnt,
// T2 XOR-swizzle (gp = gl ^ (row&7)) via pre-swizzled global src + linear gl_lds dest.
template<int RES>
__global__ __launch_bounds__(512, 2) void k_gemm256(const u16* __restrict__ A,
    const u16* __restrict__ W, const float* __restrict__ bias,
    const float* __restrict__ resid, u16* __restrict__ outb, float* __restrict__ outf){
  __shared__ union {
    u16 st[2][2][16384];     // [buf][A/B][row*64 + gp*8], 256x64 bf16 each = 128 KiB
    float cep[8][1056];      // per-wave epilogue staging [16][66] f32
  } sm;

  const int bid = blockIdx.x;
  const int wg = ((bid & 7) << 6) + (bid >> 3);   // XCD-chunked swizzle (512 % 8 == 0)
  const int m0 = (wg >> 2) << 8;                  // 128 M-tiles
  const int n0 = (wg & 3) << 8;                   // 4 N-tiles

  const int t = threadIdx.x, lane = t & 63, wid = t >> 6;
  const int ln15 = lane & 15, hi = lane >> 4;
  const int wr = wid >> 2, wc = wid & 3;

  // stage one 256x64 operand tile (32KB): 4 x gl16/thread, source pre-swizzled
  auto stage = [&](int buf, int op, const u16* __restrict__ src, int rowoff, int kt){
    #pragma unroll
    for (int i = 0; i < 4; i++){
      const int cb  = ((i << 3) + wid) << 6;          // 64-chunk wave block
      const int row = (cb >> 3) + (lane >> 3);        // 0..255
      const int gl  = (lane & 7) ^ (lane >> 3);       // logical colgroup (swizzled src)
      gl16(src + (size_t)(rowoff + row) * HIDD + (kt << 6) + (gl << 3),
           &sm.st[buf][op][cb << 3]);
    }
  };
  // fragment reads with the same XOR on the read address
  #define RD_A(c,m,ks) (*(const bf16x8*)&sm.st[c][0][((wr << 7) + ((m) << 4) + ln15) * 64 + \
                         (((((ks) << 2) + hi) ^ (lane & 7)) << 3)])
  #define RD_B(c,n,ks) (*(const bf16x8*)&sm.st[c][1][((wc << 6) + ((n) << 4) + ln15) * 64 + \
                         (((((ks) << 2) + hi) ^ (lane & 7)) << 3)])

  f32x4 acc[8][4] = {};

  // prologue: A(0),B(0) -> buf0; B(1) -> buf1
  stage(0, 0, A, m0, 0);
  stage(0, 1, W, n0, 0);
  stage(1, 1, W, n0, 1);
  asm volatile("s_waitcnt vmcnt(4)" ::: "memory");   // A0,B0 landed (B1 in flight)
  __builtin_amdgcn_s_barrier();
  asm volatile("" ::: "memory");

  const int NT = HIDD / 64;   // 16
  for (int kt = 0; kt < NT; ++kt){
    const int c = kt & 1;
    // ---- phase 1: m0-3 x all n, stage A(kt+1) -> buf c^1 ----
    bf16x8 af[4][2], bq[4][2];
    #pragma unroll
    for (int m = 0; m < 4; m++){ af[m][0] = RD_A(c, m, 0); af[m][1] = RD_A(c, m, 1); }
    #pragma unroll
    for (int n = 0; n < 4; n++){ bq[n][0] = RD_B(c, n, 0); bq[n][1] = RD_B(c, n, 1); }
    const int ka = kt + 1 < NT ? kt + 1 : NT - 1;
    stage(c ^ 1, 0, A, m0, ka);
    __builtin_amdgcn_s_setprio(1);
    #pragma unroll
    for (int m = 0; m < 4; m++)
      #pragma unroll
      for (int n = 0; n < 4; n++){
        acc[m][n] = MFMA(af[m][0], bq[n][0], acc[m][n]);
        acc[m][n] = MFMA(af[m][1], bq[n][1], acc[m][n]);
      }
    __builtin_amdgcn_s_setprio(0);
    asm volatile("" ::: "memory");
    __builtin_amdgcn_s_barrier();
    asm volatile("" ::: "memory");
    // ---- phase 2: m4-7 x all n (B reused in regs), stage B(kt+2) -> buf c ----
    #pragma unroll
    for (int m = 0; m < 4; m++){ af[m][0] = RD_A(c, m + 4, 0); af[m][1] = RD_A(c, m + 4, 1); }
    const int kb = kt + 2 < NT ? kt + 2 : NT - 1;
    stage(c, 1, W, n0, kb);
    __builtin_amdgcn_s_setprio(1);
    #pragma unroll
    for (int m = 0; m < 4; m++)
      #pragma unroll
      for (int n = 0; n < 4; n++){
        acc[m + 4][n] = MFMA(af[m][0], bq[n][0], acc[m + 4][n]);
        acc[m + 4][n] = MFMA(af[m][1], bq[n][1], acc[m + 4][n]);
      }
    __builtin_amdgcn_s_setprio(0);
    asm volatile("s_waitcnt vmcnt(4)" ::: "memory");  // A(kt+1),B(kt+1) landed; B(kt+2) in flight
    __builtin_amdgcn_s_barrier();
    asm volatile("" ::: "memory");
  }

  // ---- epilogue ----
  asm volatile("s_waitcnt vmcnt(0)" ::: "memory");    // drain tail stages before LDS reuse
  __builtin_amdgcn_s_barrier();
  asm volatile("" ::: "memory");

  float bn[4];
  #pragma unroll
  for (int n = 0; n < 4; n++) bn[n] = bias[n0 + (wc << 6) + (n << 4) + ln15];

  if constexpr (RES){
    #pragma unroll
    for (int m = 0; m < 8; m++)
      #pragma unroll
      for (int n = 0; n < 4; n++)
        #pragma unroll
        for (int r = 0; r < 4; r++){
          size_t idx = (size_t)(m0 + (wr << 7) + (m << 4) + (hi << 2) + r) * HIDD
                     + n0 + (wc << 6) + (n << 4) + ln15;
          outf[idx] = acc[m][n][r] + bn[n] + resid[idx];
        }
  } else {
    float* cw = &sm.cep[wid][0];                      // private [16][66]
    const int rr = lane >> 3, cb8 = (lane & 7) << 3;
    #pragma unroll
    for (int m = 0; m < 8; m++){
      #pragma unroll
      for (int n = 0; n < 4; n++)
        #pragma unroll
        for (int r = 0; r < 4; r++)
          cw[((hi << 2) + r) * 66 + (n << 4) + ln15] = acc[m][n][r] + bn[n];
      #pragma unroll
      for (int j = 0; j < 2; j++){
        const int row = (j << 3) + rr;
        u32 ro[4];
        #pragma unroll
        for (int p = 0; p < 4; p++){
          float v0 = cw[row * 66 + cb8 + 2 * p];
          float v1 = cw[row * 66 + cb8 + 2 * p + 1];
          ro[p] = (u32)f2bf(v0) | ((u32)f2bf(v1) << 16);
        }
        uint4 o; o.x = ro[0]; o.y = ro[1]; o.z = ro[2]; o.w = ro[3];
        *(uint4*)&outb[(size_t)(m0 + (wr << 7) + (m << 4) + row) * HIDD
                       + n0 + (wc << 6) + cb8] = o;
      }
    }
  }
  #undef RD_A
  #undef RD_B
}

// ---------------- elu + L2 norm over head_dim (in-place, q) ----------------
__global__ __launch_bounds__(256) void k_elunorm(u16* __restrict__ q){
  size_t idx = (size_t)blockIdx.x * 256 + threadIdx.x;
  uint4 u = ((const uint4*)q)[idx];
  u32 uu[4] = {u.x, u.y, u.z, u.w};
  float e[8]; float ss = 0.f;
  #pragma unroll
  for (int i = 0; i < 4; i++){
    float f0 = bf2f((u16)(uu[i] & 0xffff));
    float f1 = bf2f((u16)(uu[i] >> 16));
    f0 = f0 > 0.f ? f0 : expm1f(f0);
    f1 = f1 > 0.f ? f1 : expm1f(f1);
    e[2*i] = f0; e[2*i+1] = f1;
    ss += f0 * f0 + f1 * f1;
  }
  ss += __shfl_xor(ss, 1); ss += __shfl_xor(ss, 2); ss += __shfl_xor(ss, 4);
  float rn = rsqrtf(ss);
  u32 ro[4];
  #pragma unroll
  for (int i = 0; i < 4; i++)
    ro[i] = (u32)f2bf(e[2*i] * rn) | ((u32)f2bf(e[2*i+1] * rn) << 16);
  uint4 o; o.x = ro[0]; o.y = ro[1]; o.z = ro[2]; o.w = ro[3];
  ((uint4*)q)[idx] = o;
}

// ---------------- transpose [B,S,H,64] -> [B,H,64,S], optional elu+L2norm ----------------
template<int ELU>
__global__ __launch_bounds__(256) void k_transpose(const u16* __restrict__ in, u16* __restrict__ outp){
  __shared__ float tile[64][65];
  __shared__ float pr[64][4];
  __shared__ float rn[64];
  const int sb = blockIdx.x << 6, h = blockIdx.y, b = blockIdx.z;
  const int t = threadIdx.x;
  {
    const int tok = t >> 2, q = t & 3;
    const u16* src = in + (size_t)(b * SQ + sb + tok) * HIDD + (h << 6) + (q << 4);
    uint4 u0 = *(const uint4*)src;
    uint4 u1 = *(const uint4*)(src + 8);
    u32 uu[8] = {u0.x, u0.y, u0.z, u0.w, u1.x, u1.y, u1.z, u1.w};
    float ss = 0.f;
    #pragma unroll
    for (int i = 0; i < 8; i++){
      float f0 = bf2f((u16)(uu[i] & 0xffff));
      float f1 = bf2f((u16)(uu[i] >> 16));
      if (ELU){
        f0 = f0 > 0.f ? f0 : expm1f(f0);
        f1 = f1 > 0.f ? f1 : expm1f(f1);
        ss += f0 * f0 + f1 * f1;
      }
      tile[tok][(q << 4) + 2*i]     = f0;
      tile[tok][(q << 4) + 2*i + 1] = f1;
    }
    if (ELU) pr[tok][q] = ss;
  }
  __syncthreads();
  if (ELU){
    if (t < 64) rn[t] = rsqrtf(pr[t][0] + pr[t][1] + pr[t][2] + pr[t][3]);
    __syncthreads();
  }
  const int d = t >> 2, sq2 = (t & 3) << 4;
  u16* dst = outp + ((size_t)(b * NHQ + h) * 64 + d) * SQ + sb + sq2;
  u32 ro[8];
  #pragma unroll
  for (int i = 0; i < 8; i++){
    float v0 = tile[sq2 + 2*i][d];
    float v1 = tile[sq2 + 2*i + 1][d];
    if (ELU){ v0 *= rn[sq2 + 2*i]; v1 *= rn[sq2 + 2*i + 1]; }
    ro[i] = (u32)f2bf(v0) | ((u32)f2bf(v1) << 16);
  }
  uint4 o0; o0.x = ro[0]; o0.y = ro[1]; o0.z = ro[2]; o0.w = ro[3];
  uint4 o1; o1.x = ro[4]; o1.y = ro[5]; o1.z = ro[6]; o1.w = ro[7];
  *(uint4*)dst = o0;
  *(uint4*)(dst + 8) = o1;
}

// ---------------- kv: per (b,h)  kvT[e][d] = (1/8) * sum_s v[s][e] ek[s][d] ----------------
__global__ __launch_bounds__(256) void k_kv(const u16* __restrict__ vT, const u16* __restrict__ ekT,
                                            u16* __restrict__ kvT){
  const int bh = blockIdx.x;
  const u16* Av = vT  + (size_t)bh * 64 * SQ;
  const u16* Bk = ekT + (size_t)bh * 64 * SQ;
  const int lane = threadIdx.x & 63, wid = threadIdx.x >> 6;
  const int ln15 = lane & 15, hi = lane >> 4;
  f32x4 acc[4][4] = {};
  const int kb = wid << 10;
  for (int ks = 0; ks < 32; ++ks){
    const int k0 = kb + (ks << 5) + (hi << 3);
    bf16x8 af[4], bfr[4];
    #pragma unroll
    for (int m = 0; m < 4; m++) af[m]  = *(const bf16x8*)(Av + (size_t)((m << 4) + ln15) * SQ + k0);
    #pragma unroll
    for (int n = 0; n < 4; n++) bfr[n] = *(const bf16x8*)(Bk + (size_t)((n << 4) + ln15) * SQ + k0);
    #pragma unroll
    for (int m = 0; m < 4; m++)
      #pragma unroll
      for (int n = 0; n < 4; n++)
        acc[m][n] = MFMA(af[m], bfr[n], acc[m][n]);
  }
  __shared__ float red[64][64];
  for (int w = 0; w < 4; ++w){
    if (wid == w){
      #pragma unroll
      for (int m = 0; m < 4; m++)
        #pragma unroll
        for (int n = 0; n < 4; n++)
          #pragma unroll
          for (int r = 0; r < 4; r++){
            int row = (m << 4) + (hi << 2) + r;
            int col = (n << 4) + ln15;
            if (w == 0) red[row][col] = acc[m][n][r];
            else        red[row][col] += acc[m][n][r];
          }
    }
    __syncthreads();
  }
  u16* dst = kvT + (size_t)bh * 4096;
  const int tt = threadIdx.x;
  #pragma unroll
  for (int i = 0; i < 16; i++){
    int idx = tt * 16 + i;
    dst[idx] = f2bf(red[idx >> 6][idx & 63] * 0.125f);
  }
}

// ---------------- ctx: per (b,h,sblock) ctx[s][e] = sum_d eq[s][d] * kv[d][e] ----------------
__global__ __launch_bounds__(256) void k_ctx(const u16* __restrict__ eq, const u16* __restrict__ kvT,
                                             u16* __restrict__ ctx){
  __shared__ u16 Alds[1024 * 8];
  __shared__ u16 Blds[512 * 8];
  const int sb = blockIdx.x << 7;
  const int h = blockIdx.y, b = blockIdx.z;
  const int bh = (b << 4) + h;
  const int t = threadIdx.x, lane = t & 63, wid = t >> 6;
  const int ln15 = lane & 15, hi = lane >> 4;
  #pragma unroll
  for (int i = 0; i < 4; i++){
    int c = (wid << 6) + (i << 8) + lane;
    int g = c >> 7, row = c & 127;
    gl16(eq + (size_t)(b * SQ + sb + row) * HIDD + (h << 6) + g * 8,
         &Alds[((wid << 6) + (i << 8)) * 8]);
  }
  #pragma unroll
  for (int i = 0; i < 2; i++){
    int c = (wid << 6) + (i << 8) + lane;
    int g = c >> 6, row = c & 63;
    gl16(kvT + (size_t)bh * 4096 + (row << 6) + g * 8,
         &Blds[((wid << 6) + (i << 8)) * 8]);
  }
  asm volatile("s_waitcnt vmcnt(0)" ::: "memory");
  __syncthreads();
  f32x4 acc[2][4] = {};
  #pragma unroll
  for (int k2 = 0; k2 < 2; k2++){
    const int g = (k2 << 2) + hi;
    bf16x8 af[2], bfr[4];
    #pragma unroll
    for (int m = 0; m < 2; m++) af[m]  = *(const bf16x8*)&Alds[((g << 7) + (wid << 5) + (m << 4) + ln15) * 8];
    #pragma unroll
    for (int n = 0; n < 4; n++) bfr[n] = *(const bf16x8*)&Blds[((g << 6) + (n << 4) + ln15) * 8];
    #pragma unroll
    for (int m = 0; m < 2; m++)
      #pragma unroll
      for (int n = 0; n < 4; n++)
        acc[m][n] = MFMA(af[m], bfr[n], acc[m][n]);
  }
  #pragma unroll
  for (int m = 0; m < 2; m++)
    #pragma unroll
    for (int n = 0; n < 4; n++)
      #pragma unroll
      for (int r = 0; r < 4; r++){
        int srow = sb + (wid << 5) + (m << 4) + (hi << 2) + r;
        int col  = (n << 4) + ln15;
        ctx[(size_t)(b * SQ + srow) * HIDD + (h << 6) + col] = f2bf(acc[m][n][r]);
      }
}

extern "C" void kernel_launch(void* const* d_in, const int* in_sizes, int n_in,
                              void* d_out, int out_size, void* d_ws, size_t ws_size,
                              hipStream_t stream){
  const float* x   = (const float*)d_in[0];
  const float* lng = (const float*)d_in[2];
  const float* lnb = (const float*)d_in[3];
  const float* Wq  = (const float*)d_in[4];
  const float* bq  = (const float*)d_in[5];
  const float* Wk  = (const float*)d_in[6];
  const float* bk  = (const float*)d_in[7];
  const float* Wv  = (const float*)d_in[8];
  const float* bv  = (const float*)d_in[9];
  const float* Wo  = (const float*)d_in[10];
  const float* bo  = (const float*)d_in[11];
  float* out = (float*)d_out;

  char* w = (char*)d_ws;
  const size_t MB = 1ull << 20;
  u16* wqb  = (u16*)(w + 0   * MB);
  u16* wkb  = (u16*)(w + 2   * MB);
  u16* wvb  = (u16*)(w + 4   * MB);
  u16* wob  = (u16*)(w + 6   * MB);
  u16* xbf  = (u16*)(w + 8   * MB);
  u16* xnbf = (u16*)(w + 72  * MB);
  u16* qb   = (u16*)(w + 136 * MB);
  u16* kb   = (u16*)(w + 200 * MB);
  u16* vb   = (u16*)(w + 264 * MB);
  u16* kvT  = (u16*)(w + 328 * MB);
  u16* ekT = xnbf;
  u16* vT  = xbf;
  u16* ctx = kb;

  k_cast<<<1024, 256, 0, stream>>>(Wq, wqb);
  k_cast<<<1024, 256, 0, stream>>>(Wk, wkb);
  k_cast<<<1024, 256, 0, stream>>>(Wv, wvb);
  k_cast<<<1024, 256, 0, stream>>>(Wo, wob);
  k_ln<<<TOKN, 256, 0, stream>>>(x, lng, lnb, xbf, xnbf);
  k_gemm256<0><<<512, 512, 0, stream>>>(xnbf, wqb, bq, nullptr, qb, nullptr);
  k_gemm256<0><<<512, 512, 0, stream>>>(xbf,  wkb, bk, nullptr, kb, nullptr);
  k_gemm256<0><<<512, 512, 0, stream>>>(xbf,  wvb, bv, nullptr, vb, nullptr);
  k_elunorm<<<16384, 256, 0, stream>>>(qb);
  k_transpose<1><<<dim3(64, 16, 8), 256, 0, stream>>>(kb, ekT);
  k_transpose<0><<<dim3(64, 16, 8), 256, 0, stream>>>(vb, vT);
  k_kv<<<128, 256, 0, stream>>>(vT, ekT, kvT);
  k_ctx<<<dim3(32, 16, 8), 256, 0, stream>>>(qb, kvT, ctx);
  k_gemm256<1><<<512, 512, 0, stream>>>(ctx, wob, bo, x, nullptr, out);

  (void)in_sizes; (void)n_in; (void)out_size; (void)ws_size;
}